// Round 6
// baseline (58.386 us; speedup 1.0000x reference)
//
#include <hip/hip_runtime.h>

// L=32768, N=32, E=H=1, BS=256 -> 4096 rank-1 softmax problems:
//   s_ij = a_i*k_j (scale=1), out_i = sum_j 2^(a_i*k_j*log2e... folded) v_j / den.
// TRANS-pipe bound at ~40us across R1/R3/R5 -> replace v_exp_f32 with packed
// VALU exp2: magic-const range reduction + deg-4 poly + int exponent attach.
// Max-subtraction dropped: |arg|<=~45, 2^n stays normal f32, softmax is
// scale-invariant. No reductions, one barrier, one fused kernel.

#define LL   32768
#define NN   32
#define BSZ  256
#define NBLK (LL / BSZ)
#define LOG2E 1.4426950408889634f

typedef float v2f __attribute__((ext_vector_type(2)));

// 2^f Taylor coefficients (deg 4), f in [-0.5, 0.5]; rel err ~4e-5
#define C1 0.6931471805599453f
#define C2 0.2402265069591007f
#define C3 0.0555041086648216f
#define C4 0.0096181291076285f
#define MAGICF 12582912.0f   // 1.5 * 2^23

__global__ __launch_bounds__(256, 2) void BlockCrossAttn_kernel(
    const float* __restrict__ q_in, const float* __restrict__ k_in,
    const float* __restrict__ v_in,
    const float* __restrict__ ipw,  const float* __restrict__ ipb,
    const float* __restrict__ opw,  const float* __restrict__ opb,
    float* __restrict__ out)
{
    const int blk = blockIdx.x >> 5;   // row-block b in [0,128)
    const int n   = blockIdx.x & 31;   // batch
    const int tid = threadIdx.x;       // row within block

    const float wq = ipw[0], wk = ipw[1], wv = ipw[2];
    const float bq = ipb[0], bk = ipb[1], bv = ipb[2];
    const float wo = opw[0], bo = opb[0];

    __shared__ alignas(16) float sk[BSZ];
    __shared__ alignas(16) float sv[BSZ];

    const int gidx = (blk * BSZ + tid) * NN + n;

    const float a = fmaf(q_in[gidx], wq, bq) * LOG2E;  // log2-domain coeff
    sk[tid] = fmaf(k_in[gidx], wk, bk);
    sv[tid] = fmaf(v_in[gidx], wv, bv);
    __syncthreads();

    const v2f av = {a, a};
    const v2f MG = {MAGICF, MAGICF};
    const v2f c4 = {C4, C4}, c3 = {C3, C3}, c2 = {C2, C2}, c1 = {C1, C1};
    const v2f one = {1.0f, 1.0f};

    v2f den0 = {0.f, 0.f}, den1 = {0.f, 0.f};
    v2f num0 = {0.f, 0.f}, num1 = {0.f, 0.f};

    const float4* k4p = (const float4*)sk;
    const float4* v4p = (const float4*)sv;

    #pragma unroll 4
    for (int t = 0; t < BSZ / 4; ++t) {
        const float4 k4 = k4p[t];       // ds_read_b128, uniform addr (broadcast)
        const float4 v4 = v4p[t];

        const v2f argA = av * (v2f){k4.x, k4.y};     // v_pk_mul_f32
        const v2f argB = av * (v2f){k4.z, k4.w};
        const v2f yA = argA + MG;                    // round-to-int in mantissa
        const v2f yB = argB + MG;
        const v2f nA = yA - MG;                      // n as float (exact)
        const v2f nB = yB - MG;
        const v2f fA = argA - nA;                    // f in [-0.5,0.5] (exact)
        const v2f fB = argB - nB;

        v2f pA = __builtin_elementwise_fma(c4, fA, c3);
        v2f pB = __builtin_elementwise_fma(c4, fB, c3);
        pA = __builtin_elementwise_fma(pA, fA, c2);
        pB = __builtin_elementwise_fma(pB, fB, c2);
        pA = __builtin_elementwise_fma(pA, fA, c1);
        pB = __builtin_elementwise_fma(pB, fB, c1);
        pA = __builtin_elementwise_fma(pA, fA, one); // 2^f
        pB = __builtin_elementwise_fma(pB, fB, one);

        // attach exponent: r = bits(p) + (bits(y)<<23)  (bias bits shift out)
        v2f rA, rB;
        rA.x = __int_as_float(__float_as_int(pA.x) + (__float_as_int(yA.x) << 23));
        rA.y = __int_as_float(__float_as_int(pA.y) + (__float_as_int(yA.y) << 23));
        rB.x = __int_as_float(__float_as_int(pB.x) + (__float_as_int(yB.x) << 23));
        rB.y = __int_as_float(__float_as_int(pB.y) + (__float_as_int(yB.y) << 23));

        den0 += rA;                                   // v_pk_add_f32
        den1 += rB;
        num0 = __builtin_elementwise_fma(rA, (v2f){v4.x, v4.y}, num0);
        num1 = __builtin_elementwise_fma(rB, (v2f){v4.z, v4.w}, num1);
    }

    const float den = (den0.x + den0.y) + (den1.x + den1.y);
    const float num = (num0.x + num0.y) + (num1.x + num1.y);
    out[gidx] = fmaf(num / den, wo, bo);
}

extern "C" void kernel_launch(void* const* d_in, const int* in_sizes, int n_in,
                              void* d_out, int out_size, void* d_ws, size_t ws_size,
                              hipStream_t stream) {
    const float* q   = (const float*)d_in[0];
    const float* k   = (const float*)d_in[1];
    const float* v   = (const float*)d_in[2];
    const float* ipw = (const float*)d_in[3];
    const float* ipb = (const float*)d_in[4];
    const float* opw = (const float*)d_in[5];
    const float* opb = (const float*)d_in[6];
    float* out = (float*)d_out;

    dim3 grid(NBLK * NN);   // 4096 workgroups: one per (block, batch)
    dim3 block(BSZ);        // one thread per row
    BlockCrossAttn_kernel<<<grid, block, 0, stream>>>(q, k, v, ipw, ipb, opw, opb, out);
}

// Round 7
// 53.401 us; speedup vs baseline: 1.0934x; 1.0934x over previous
//
#include <hip/hip_runtime.h>

// L=32768, N=32, E=H=1, BS=256 -> 4096 rank-1 softmax problems:
//   s_ij = a_i*k_j (scale=1), out_i = sum_j 2^(a_i'*k_j) v_j / den  (a' = a*log2e).
//
// R7: LDS pipe was the 41us plateau (8192 ds_read_b128/CU x 12cy = 98k cy).
// Feed k/v through the SCALAR pipe instead: prepass transposes to [N][L] planes,
// attn kernel streams k/v via inline-asm s_load_dwordx16 into SGPRs (waitcnt
// inside the asm block -> safe). Inner loop: 3 VALU + 1 v_exp per j, zero LDS,
// zero VMEM. Max-subtraction dropped (|arg|<=~40 log2 units, f32-safe).

#define LL   32768
#define NN   32
#define BSZ  256
#define NBLK (LL / BSZ)
#define LOG2E 1.4426950408889634f

typedef float sf16 __attribute__((ext_vector_type(16)));

// ---------------- Kernel P: projection + transpose (verified R3) ----------
// grid = L/32 = 1024 WGs, 256 threads. Tile: 32 rows x 32 batches per array.
__global__ __launch_bounds__(256) void proj_transpose_kernel(
    const float* __restrict__ q_in, const float* __restrict__ k_in,
    const float* __restrict__ v_in,
    const float* __restrict__ ipw,  const float* __restrict__ ipb,
    float* __restrict__ ws)
{
    __shared__ float sa[32][33], sk[32][33], sv[32][33];
    const int t  = threadIdx.x;
    const int r0 = blockIdx.x * 32;

    const float wq = ipw[0], wk = ipw[1], wv = ipw[2];
    const float bq = ipb[0], bk = ipb[1], bv = ipb[2];

    const int f = r0 * NN + t * 4;     // coalesced: 4 consecutive n of one row
    const float4 q4 = *reinterpret_cast<const float4*>(q_in + f);
    const float4 k4 = *reinterpret_cast<const float4*>(k_in + f);
    const float4 v4 = *reinterpret_cast<const float4*>(v_in + f);

    const int row = t >> 3, nc = (t & 7) * 4;
    sa[row][nc + 0] = fmaf(q4.x, wq, bq) * LOG2E;
    sa[row][nc + 1] = fmaf(q4.y, wq, bq) * LOG2E;
    sa[row][nc + 2] = fmaf(q4.z, wq, bq) * LOG2E;
    sa[row][nc + 3] = fmaf(q4.w, wq, bq) * LOG2E;
    sk[row][nc + 0] = fmaf(k4.x, wk, bk);
    sk[row][nc + 1] = fmaf(k4.y, wk, bk);
    sk[row][nc + 2] = fmaf(k4.z, wk, bk);
    sk[row][nc + 3] = fmaf(k4.w, wk, bk);
    sv[row][nc + 0] = fmaf(v4.x, wv, bv);
    sv[row][nc + 1] = fmaf(v4.y, wv, bv);
    sv[row][nc + 2] = fmaf(v4.z, wv, bv);
    sv[row][nc + 3] = fmaf(v4.w, wv, bv);
    __syncthreads();

    float* __restrict__ A = ws;
    float* __restrict__ K = ws + (size_t)LL * NN;
    float* __restrict__ V = ws + (size_t)2 * LL * NN;
    const int n = t >> 3, j0 = (t & 7) * 4;  // coalesced: 4 consecutive rows

    float4 o;
    o.x = sa[j0 + 0][n]; o.y = sa[j0 + 1][n]; o.z = sa[j0 + 2][n]; o.w = sa[j0 + 3][n];
    *reinterpret_cast<float4*>(A + (size_t)n * LL + r0 + j0) = o;
    o.x = sk[j0 + 0][n]; o.y = sk[j0 + 1][n]; o.z = sk[j0 + 2][n]; o.w = sk[j0 + 3][n];
    *reinterpret_cast<float4*>(K + (size_t)n * LL + r0 + j0) = o;
    o.x = sv[j0 + 0][n]; o.y = sv[j0 + 1][n]; o.z = sv[j0 + 2][n]; o.w = sv[j0 + 3][n];
    *reinterpret_cast<float4*>(V + (size_t)n * LL + r0 + j0) = o;
}

// ---------------- Kernel A: rank-1 softmax, scalar-pipe k/v ----------------
// grid = 4096 WGs, 256 threads = 1 row each. No LDS, no barrier, no VMEM loop.
__global__ __launch_bounds__(256) void attn_kernel(
    const float* __restrict__ ws,
    const float* __restrict__ opw, const float* __restrict__ opb,
    float* __restrict__ out)
{
    const int g   = blockIdx.x;
    const int blk = g >> 5;
    const int n   = g & 31;
    const int tid = threadIdx.x;

    const float* __restrict__ A = ws;
    const float* __restrict__ K = ws + (size_t)LL * NN;
    const float* __restrict__ V = ws + (size_t)2 * LL * NN;
    const int base = n * LL + blk * BSZ;       // wave-uniform

    const float a = A[base + tid];             // per-lane, coalesced (has LOG2E)

    const float* kp = K + base;                // uniform -> SGPR pair
    const float* vp = V + base;

    float den0 = 0.f, den1 = 0.f, num0 = 0.f, num1 = 0.f;

    #pragma unroll
    for (int c = 0; c < BSZ / 16; ++c) {
        sf16 kc, vc;
        // SMEM loads + wait fused in one volatile asm: hardware-safe (lgkmcnt(0)
        // covers out-of-order SMEM returns); consumers data-depend on outputs.
        asm volatile(
            "s_load_dwordx16 %0, %2, 0x0\n\t"
            "s_load_dwordx16 %1, %3, 0x0\n\t"
            "s_waitcnt lgkmcnt(0)"
            : "=s"(kc), "=s"(vc)
            : "s"(kp + c * 16), "s"(vp + c * 16));

        #pragma unroll
        for (int j = 0; j < 16; j += 2) {
            const float p0 = __builtin_amdgcn_exp2f(a * kc[j]);
            const float p1 = __builtin_amdgcn_exp2f(a * kc[j + 1]);
            den0 += p0;
            den1 += p1;
            num0 = fmaf(p0, vc[j],     num0);
            num1 = fmaf(p1, vc[j + 1], num1);
        }
    }

    const float o = (num0 + num1) / (den0 + den1);
    out[(size_t)(blk * BSZ + tid) * NN + n] = fmaf(o, opw[0], opb[0]);
}

extern "C" void kernel_launch(void* const* d_in, const int* in_sizes, int n_in,
                              void* d_out, int out_size, void* d_ws, size_t ws_size,
                              hipStream_t stream) {
    const float* q   = (const float*)d_in[0];
    const float* k   = (const float*)d_in[1];
    const float* v   = (const float*)d_in[2];
    const float* ipw = (const float*)d_in[3];
    const float* ipb = (const float*)d_in[4];
    const float* opw = (const float*)d_in[5];
    const float* opb = (const float*)d_in[6];
    float* out = (float*)d_out;
    float* ws  = (float*)d_ws;   // needs 3*L*N*4 = 12.6 MB

    proj_transpose_kernel<<<dim3(LL / 32), dim3(256), 0, stream>>>(q, k, v, ipw, ipb, ws);
    attn_kernel<<<dim3(NBLK * NN), dim3(256), 0, stream>>>(ws, opw, opb, out);
}

// Round 8
// 41.791 us; speedup vs baseline: 1.3971x; 1.2778x over previous
//
#include <hip/hip_runtime.h>

// L=32768, N=32, E=H=1, BS=256 -> 4096 rank-1 softmax problems:
//   s_ij = a_i*k_j (scale=1), out_i = sum_j 2^(a'_i k_j) v_j / sum_j 2^(a'_i k_j),
//   a' = a*log2e. Max-subtraction dropped: |arg| <= ~38 log2 units, 2^x stays
//   in normal f32 range, softmax is scale-invariant (validated R5-R7).
//
// Model (R1-R7 calibration): issue-bound at ~16cy/j (mul 2 + exp ~10 + add 2 +
// fmac 2) x 256 j x 16 waves/SIMD = 65.5k cy = 27us floor; prior rounds ran at
// ~60-65% issue efficiency. R8: kill the reduction prologue + barrier #2, and
// run 8 independent accumulator chains with 16 j in flight to hide exp latency.

#define LL   32768
#define NN   32
#define BSZ  256
#define NBLK (LL / BSZ)
#define LOG2E 1.4426950408889634f

__global__ __launch_bounds__(256) void BlockCrossAttn_kernel(
    const float* __restrict__ q_in, const float* __restrict__ k_in,
    const float* __restrict__ v_in,
    const float* __restrict__ ipw,  const float* __restrict__ ipb,
    const float* __restrict__ opw,  const float* __restrict__ opb,
    float* __restrict__ out)
{
    const int blk = blockIdx.x >> 5;   // row-block b in [0,128)
    const int n   = blockIdx.x & 31;   // batch
    const int tid = threadIdx.x;       // row within block

    const float wq = ipw[0], wk = ipw[1], wv = ipw[2];
    const float bq = ipb[0], bk = ipb[1], bv = ipb[2];

    __shared__ alignas(16) float sk[BSZ];
    __shared__ alignas(16) float sv[BSZ];

    const int gidx = (blk * BSZ + tid) * NN + n;

    const float a = fmaf(q_in[gidx], wq, bq) * LOG2E;  // log2-domain row coeff
    sk[tid] = fmaf(k_in[gidx], wk, bk);
    sv[tid] = fmaf(v_in[gidx], wv, bv);
    __syncthreads();

    // 8 independent chains; 16 j in flight per unrolled body.
    float den0 = 0.f, den1 = 0.f, den2 = 0.f, den3 = 0.f;
    float num0 = 0.f, num1 = 0.f, num2 = 0.f, num3 = 0.f;

    const float4* __restrict__ k4p = (const float4*)sk;
    const float4* __restrict__ v4p = (const float4*)sv;

    #pragma unroll 4
    for (int t = 0; t < BSZ / 4; ++t) {
        const float4 k4 = k4p[t];      // ds_read_b128, uniform addr (broadcast)
        const float4 v4 = v4p[t];
        const float p0 = __builtin_amdgcn_exp2f(a * k4.x);
        const float p1 = __builtin_amdgcn_exp2f(a * k4.y);
        const float p2 = __builtin_amdgcn_exp2f(a * k4.z);
        const float p3 = __builtin_amdgcn_exp2f(a * k4.w);
        den0 += p0; den1 += p1; den2 += p2; den3 += p3;
        num0 = fmaf(p0, v4.x, num0);
        num1 = fmaf(p1, v4.y, num1);
        num2 = fmaf(p2, v4.z, num2);
        num3 = fmaf(p3, v4.w, num3);
    }

    const float den = (den0 + den1) + (den2 + den3);
    const float num = (num0 + num1) + (num2 + num3);
    out[gidx] = fmaf(num / den, opw[0], opb[0]);
}

extern "C" void kernel_launch(void* const* d_in, const int* in_sizes, int n_in,
                              void* d_out, int out_size, void* d_ws, size_t ws_size,
                              hipStream_t stream) {
    const float* q   = (const float*)d_in[0];
    const float* k   = (const float*)d_in[1];
    const float* v   = (const float*)d_in[2];
    const float* ipw = (const float*)d_in[3];
    const float* ipb = (const float*)d_in[4];
    const float* opw = (const float*)d_in[5];
    const float* opb = (const float*)d_in[6];
    float* out = (float*)d_out;

    dim3 grid(NBLK * NN);   // 4096 workgroups: one per (block, batch)
    dim3 block(BSZ);        // one thread per row
    BlockCrossAttn_kernel<<<grid, block, 0, stream>>>(q, k, v, ipw, ipb, opw, opb, out);
}